// Round 5
// baseline (80.067 us; speedup 1.0000x reference)
//
#include <hip/hip_runtime.h>
#include <math.h>

// ColBERT pairwise late-interaction score — single kernel, split-j (R5).
//
// out[b,o] = scale/sqrt(Lq*Lk) * sum_i log(sum_j exp(alpha*qn[b,i].kn[o,j]))/alpha
// Row b is exactly zero if any q_mask[b,i] (reference isfinite guard) -> only
// M ~ 2-3 of 64 b's are live; dead (b,o) outputs are zeroed directly.
//
// R5 structure: grid = 256 blocks, 2 per o (h = half). Each block stages 128
// of the 256 k rows (64 KB fp32 -> f16 LDS), so all 256 CUs share the one
// mandatory 16 MB k sweep (R4 used 128 blocks: half the CUs, 2x the per-CU
// bytes). Liveness (q_mask scan) is issued before the k loads in wave 0 and
// retires while k loads are in flight.
//
// Cross-block combine: per-(b,i) partial exp-sums go to d_ws via device-scope
// relaxed atomic stores (per-XCD L2s are NOT coherent; plain stores unsafe),
// then atomicExch on a per-o flag. d_ws is poisoned 0xAAAAAAAA, which serves
// as the "I'm first" sentinel: exactly one block of the pair observes the
// other's magic and finalizes (log, row-sum, scale) — no init kernel needed.
//
// Numerics: S <= 1 (cosine), alpha*S <= 12 -> exp safe; masked j add -1e30
// before exp -> exact 0; valid j contribute >= e^-12 so combined sum == 0
// iff the row is fully k-masked (-inf -> zero output). f16 rounding ~1e-3,
// threshold 5.1e-2 (R3/R4 passed with identical math).

#define ALPHA 12.0f

constexpr int B_  = 64;
constexpr int LQ  = 32;
constexpr int O_  = 128;
constexpr int LK  = 256;
constexpr int D_  = 128;
constexpr int JB  = 128;           // k rows per block (half of LK)
constexpr int LDH = D_ + 8;        // f16 row stride: pad keeps b128 frag reads
                                   // spread across banks

typedef _Float16 half8   __attribute__((ext_vector_type(8)));
typedef _Float16 half4_t __attribute__((ext_vector_type(4)));
typedef float    f32x4   __attribute__((ext_vector_type(4)));

#define FLAG_MAGIC 0x13570000

__global__ __launch_bounds__(256, 1)
void colbert_split_kernel(const float* __restrict__ q,       // [B, Lq, D]
                          const float* __restrict__ k,       // [O, Lk, D]
                          const int*  __restrict__ q_mask,   // [B, Lq]
                          const int*  __restrict__ k_mask,   // [O, Lk]
                          const float* __restrict__ logit_scale,
                          float* __restrict__ out,           // [B, O]
                          float* __restrict__ wpart,         // [O][2][B][LQ]
                          int*   __restrict__ wflag)         // [O]
{
    __shared__ _Float16 kl[JB][LDH];   // 34816 B
    __shared__ _Float16 ql[LQ][LDH];   //  8704 B
    __shared__ float rk[JB];
    __shared__ float bjs[JB];          // 0 or -1e30
    __shared__ float rqa[LQ];          // ALPHA/||q_i||
    __shared__ float part[2][LQ];
    __shared__ int   lbm[B_ + 1];      // [0]=M, [1+m]=live b
    __shared__ int   lastf;

    const int o     = blockIdx.x >> 1;
    const int h     = blockIdx.x & 1;
    const int t     = threadIdx.x;
    const int lane  = t & 63;
    const int w     = t >> 6;
    const int row16 = lane & 15;
    const int quad  = lane >> 4;

    // ---- wave 0: issue q_mask loads FIRST (oldest in vmcnt order) ----
    int4 mm[8];
    if (w == 0) {
        const int4* qm4 = (const int4*)q_mask;   // 512 int4 over [64][32]
        #pragma unroll
        for (int u = 0; u < 8; ++u)
            mm[u] = qm4[lane * 8 + u];           // lane covers b = lane
    }

    // ---- all threads: issue k loads (stay in flight during mask work) ----
    const float4* kg = (const float4*)(k + ((size_t)o * LK + h * JB) * D_);
    float4 kv[16];
    #pragma unroll
    for (int r = 0; r < 16; ++r)
        kv[r] = kg[t + 256 * r];                 // [128][32] float4, coalesced

    // ---- wave 0: process masks (waits only on mm, not kv) ----
    if (w == 0) {
        int any = 0;
        #pragma unroll
        for (int u = 0; u < 8; ++u)
            any |= mm[u].x | mm[u].y | mm[u].z | mm[u].w;
        bool live = (any == 0);
        unsigned long long mball = __ballot(live);
        if (live) {
            int rank = __popcll(mball & ((1ull << lane) - 1ull));
            lbm[1 + rank] = lane;
        } else {
            out[lane * O_ + o] = 0.0f;           // dead row -> exact zero
        }
        if (lane == 0) lbm[0] = (int)__popcll(mball);
    }

    // ---- convert k tile to f16 LDS ----
    #pragma unroll
    for (int r = 0; r < 16; ++r) {
        int idx = t + 256 * r;
        int j = idx >> 5, c4 = idx & 31;
        half4_t hh;
        hh[0] = (_Float16)kv[r].x; hh[1] = (_Float16)kv[r].y;
        hh[2] = (_Float16)kv[r].z; hh[3] = (_Float16)kv[r].w;
        *(half4_t*)&kl[j][c4 * 4] = hh;
    }
    __syncthreads();

    const int M = lbm[0];
    if (M == 0) return;                          // all outputs already zeroed

    // ---- k norms + mask bias: t<128 owns local row t ----
    if (t < JB) {
        float ss = 0.f;
        #pragma unroll
        for (int p = 0; p < 16; ++p) {
            half8 hh = *(const half8*)&kl[t][p * 8];
            #pragma unroll
            for (int e = 0; e < 8; ++e) {
                float x = (float)hh[e];
                ss = fmaf(x, x, ss);
            }
        }
        rk[t]  = 1.0f / fmaxf(sqrtf(ss), 1e-12f);
        bjs[t] = (k_mask[o * LK + h * JB + t] != 0) ? -1e30f : 0.0f;
    }
    // first in-loop barrier makes rk/bjs visible before MFMA phase

    // ---- per live b ----
    for (int m = 0; m < M; ++m) {
        const int b = lbm[1 + m];

        const float4* qg = (const float4*)(q + (size_t)b * LQ * D_);
        #pragma unroll
        for (int r = 0; r < 4; ++r) {
            int idx = t + 256 * r;               // [32][32] float4
            float4 v = qg[idx];
            int i = idx >> 5, c4 = idx & 31;
            half4_t hh;
            hh[0] = (_Float16)v.x; hh[1] = (_Float16)v.y;
            hh[2] = (_Float16)v.z; hh[3] = (_Float16)v.w;
            *(half4_t*)&ql[i][c4 * 4] = hh;
        }
        __syncthreads();                         // ql (+rk/bjs on iter 0)

        if (t < LQ) {
            float ss = 0.f;
            #pragma unroll
            for (int p = 0; p < 16; ++p) {
                half8 hh = *(const half8*)&ql[t][p * 8];
                #pragma unroll
                for (int e = 0; e < 8; ++e) {
                    float x = (float)hh[e];
                    ss = fmaf(x, x, ss);
                }
            }
            rqa[t] = ALPHA / fmaxf(sqrtf(ss), 1e-12f);
        }
        __syncthreads();

        // MFMA: wave w -> rows [16*(w>>1), +16), local cols [(w&1)*64, +64)
        const int i0 = (w >> 1) * 16;
        const int j0 = (w & 1) * 64;

        half8 afrag[4];
        #pragma unroll
        for (int kk = 0; kk < 4; ++kk)
            afrag[kk] = *(const half8*)&ql[i0 + row16][kk * 32 + quad * 8];

        float rqv[4];
        #pragma unroll
        for (int rg = 0; rg < 4; ++rg)
            rqv[rg] = rqa[i0 + quad * 4 + rg];

        float esum[4] = {0.f, 0.f, 0.f, 0.f};
        #pragma unroll
        for (int c = 0; c < 4; ++c) {
            const int jt = j0 + c * 16;
            f32x4 acc = {0.f, 0.f, 0.f, 0.f};
            #pragma unroll
            for (int kk = 0; kk < 4; ++kk) {
                half8 bfrag = *(const half8*)&kl[jt + row16][kk * 32 + quad * 8];
                acc = __builtin_amdgcn_mfma_f32_16x16x32_f16(afrag[kk], bfrag,
                                                             acc, 0, 0, 0);
            }
            // C layout: col = lane&15 (j), row = quad*4+reg (i)
            const float rkj = rk[jt + row16];
            const float bb  = bjs[jt + row16];
            #pragma unroll
            for (int rg = 0; rg < 4; ++rg)
                esum[rg] += __expf(acc[rg] * rqv[rg] * rkj + bb);
        }
        #pragma unroll
        for (int rg = 0; rg < 4; ++rg) {
            float e = esum[rg];
            e += __shfl_xor(e, 1);
            e += __shfl_xor(e, 2);
            e += __shfl_xor(e, 4);
            e += __shfl_xor(e, 8);
            esum[rg] = e;
        }
        if (row16 == 0) {
            #pragma unroll
            for (int rg = 0; rg < 4; ++rg)
                part[w & 1][i0 + quad * 4 + rg] = esum[rg];
        }
        __syncthreads();

        // block partial for (b, i): sum over this block's 128 j's.
        // Device-scope atomic store: per-XCD L2 not coherent for plain stores.
        if (t < LQ) {
            float bsum = part[0][t] + part[1][t];
            float* slot = &wpart[(((size_t)o * 2 + h) * B_ + b) * LQ + t];
            __hip_atomic_store(slot, bsum, __ATOMIC_RELAXED,
                               __HIP_MEMORY_SCOPE_AGENT);
        }
        __syncthreads();   // part reads done + atomic stores drained (vmcnt)
    }

    // ---- pair rendezvous: poison 0xAAAAAAAA acts as "first" sentinel ----
    if (t == 0) {
        int old = __hip_atomic_exchange(&wflag[o], FLAG_MAGIC | h,
                                        __ATOMIC_ACQ_REL,
                                        __HIP_MEMORY_SCOPE_AGENT);
        lastf = (old == (FLAG_MAGIC | (1 - h)));
    }
    __syncthreads();
    if (!lastf) return;

    // ---- finalizer (exactly one block per o): combine halves ----
    const float scale  = fminf(__expf(logit_scale[0]), 100.0f);
    const float inv_ln = 1.0f / (sqrtf((float)(LQ * LK)) + 1e-6f);
    if (t < 64) {
        for (int m = 0; m < M; ++m) {
            const int b = lbm[1 + m];
            float s = 0.f, lse = 0.f;
            bool badrow = false;
            if (t < LQ) {
                const float* s0 = &wpart[(((size_t)o * 2 + 0) * B_ + b) * LQ + t];
                const float* s1 = &wpart[(((size_t)o * 2 + 1) * B_ + b) * LQ + t];
                float p0 = __hip_atomic_load(s0, __ATOMIC_RELAXED,
                                             __HIP_MEMORY_SCOPE_AGENT);
                float p1 = __hip_atomic_load(s1, __ATOMIC_RELAXED,
                                             __HIP_MEMORY_SCOPE_AGENT);
                s = p0 + p1;
                badrow = (s <= 0.f);             // row fully k-masked -> -inf
                lse = __logf(fmaxf(s, 1e-38f));
            }
            unsigned long long zb = __ballot(badrow);
            float tot = lse;                     // lanes >= 32 contribute 0
            tot += __shfl_xor(tot, 16);
            tot += __shfl_xor(tot, 8);
            tot += __shfl_xor(tot, 4);
            tot += __shfl_xor(tot, 2);
            tot += __shfl_xor(tot, 1);
            if (t == 0) {
                float res = 0.f;
                if (zb == 0ULL)
                    res = (tot * (1.0f / ALPHA)) * inv_ln * scale;
                out[b * O_ + o] = res;
            }
        }
    }
}

extern "C" void kernel_launch(void* const* d_in, const int* in_sizes, int n_in,
                              void* d_out, int out_size, void* d_ws, size_t ws_size,
                              hipStream_t stream) {
    const float* q           = (const float*)d_in[0];
    const float* k           = (const float*)d_in[1];
    const int*   q_mask      = (const int*)d_in[2];
    const int*   k_mask      = (const int*)d_in[3];
    const float* logit_scale = (const float*)d_in[4];
    float* out = (float*)d_out;

    float* wpart = (float*)d_ws;                       // O*2*B*LQ floats = 2 MB
    int*   wflag = (int*)((char*)d_ws + (size_t)O_ * 2 * B_ * LQ * sizeof(float));

    colbert_split_kernel<<<2 * O_, 256, 0, stream>>>(q, k, q_mask, k_mask,
                                                     logit_scale, out,
                                                     wpart, wflag);
}

// Round 6
// 76.971 us; speedup vs baseline: 1.0402x; 1.0402x over previous
//
#include <hip/hip_runtime.h>
#include <math.h>

// ColBERT pairwise late-interaction score — single fused kernel (R6).
//
// out[b,o] = scale/sqrt(Lq*Lk) * sum_i log(sum_j exp(alpha*qn[b,i].kn[o,j]))/alpha
// Row b is exactly zero if any q_mask[b,i] (reference isfinite guard) -> only
// M ~ 2-3 of 64 b's are live.
//
// R6 = R4 structure (grid = 128 blocks, one per o; R5's split-j + cross-block
// rendezvous REGRESSED 12 -> 16 us) with two fixes:
//   1. Liveness with zero front-end serialization: every wave redundantly
//      loads all 8 KB of q_mask FIRST (oldest in vmcnt order), then issues
//      its k-tile loads; ballot-per-wave -> no LDS, no barrier, and the mask
//      processing retires while k loads are in flight.
//   2. Live b's processed in PAIRS: the B (k-tile) MFMA fragments are
//      identical for every b, and their ds_read_b128 pattern is structurally
//      8-way bank-grouped (any 16B-aligned layout caps at 8 of 32 banks), so
//      one B-frag read now feeds two MFMAs — halves the dominant LDS traffic
//      (~36 b128/wave/b -> ~40 for 2 b's).
//
// Numerics: S <= 1 (cosine) -> alpha*S <= 12, exp never overflows; masked j
// add -1e30 before exp -> exact 0; valid j >= e^-12 so rowsum == 0 iff row
// fully k-masked (-inf -> zero). f16 input rounding ~1e-3 vs 5.1e-2 threshold.

#define ALPHA 12.0f

constexpr int B_  = 64;
constexpr int LQ  = 32;
constexpr int O_  = 128;
constexpr int LK  = 256;
constexpr int D_  = 128;
constexpr int LDH = D_ + 8;        // f16 row stride 136 (272 B), 16B-aligned

typedef _Float16 half8   __attribute__((ext_vector_type(8)));
typedef _Float16 half4_t __attribute__((ext_vector_type(4)));
typedef float    f32x4   __attribute__((ext_vector_type(4)));

__global__ __launch_bounds__(256, 1)
void colbert_fused_kernel(const float* __restrict__ q,       // [B, Lq, D]
                          const float* __restrict__ k,       // [O, Lk, D]
                          const int*  __restrict__ q_mask,   // [B, Lq] 0/1
                          const int*  __restrict__ k_mask,   // [O, Lk] 0/1
                          const float* __restrict__ logit_scale,
                          float* __restrict__ out)           // [B, O]
{
    __shared__ _Float16 kl[LK][LDH];        // 69632 B
    __shared__ _Float16 ql2[2][LQ][LDH];    // 17408 B (pair of q tiles)
    __shared__ float rk[LK];                // 1/||k_j||
    __shared__ float bjs[LK];               // 0 or -1e30
    __shared__ float rqa2[2][LQ];           // ALPHA/||q_i|| per pair member
    __shared__ float part2[2][2][LQ];       // [pair][col-half][row]

    const int o     = blockIdx.x;
    const int t     = threadIdx.x;
    const int lane  = t & 63;
    const int w     = t >> 6;
    const int row16 = lane & 15;
    const int quad  = lane >> 4;

    // ---- 1. q_mask loads FIRST (oldest in vmcnt): every wave, all 8 KB ----
    int4 mm[8];
    {
        const int4* qm4 = (const int4*)q_mask;     // 512 int4 over [64][32]
        #pragma unroll
        for (int u = 0; u < 8; ++u)
            mm[u] = qm4[lane * 8 + u];             // lane <-> b = lane
    }

    // ---- 2. issue k half-tile 0 + small loads (stay in flight) ----
    const float4* kg = (const float4*)(k + (size_t)o * LK * D_);
    float4 kv[16];
    #pragma unroll
    for (int r = 0; r < 16; ++r)
        kv[r] = kg[t + 256 * r];                   // rows 0..127, coalesced
    const int   km = k_mask[o * LK + t];           // row j = t
    const float ls = logit_scale[0];

    // ---- 3. mask processing (waits only on mm; k loads still in flight) ----
    int any = 0;
    #pragma unroll
    for (int u = 0; u < 8; ++u)
        any |= mm[u].x | mm[u].y | mm[u].z | mm[u].w;
    const bool live = (any == 0);
    const unsigned long long mball = __ballot(live);   // same in every wave
    if (w == 0 && !live) out[lane * O_ + o] = 0.0f;    // dead row -> 0
    const int M = (int)__popcll(mball);
    if (M == 0) return;                                // block-uniform

    // ---- 4. convert half 0, load+convert half 1 ----
    #pragma unroll
    for (int r = 0; r < 16; ++r) {
        int idx = t + 256 * r;
        int j = idx >> 5, c4 = idx & 31;
        half4_t hh;
        hh[0] = (_Float16)kv[r].x; hh[1] = (_Float16)kv[r].y;
        hh[2] = (_Float16)kv[r].z; hh[3] = (_Float16)kv[r].w;
        *(half4_t*)&kl[j][c4 * 4] = hh;
    }
    #pragma unroll
    for (int r = 0; r < 16; ++r)
        kv[r] = kg[4096 + t + 256 * r];            // rows 128..255
    #pragma unroll
    for (int r = 0; r < 16; ++r) {
        int idx = 4096 + t + 256 * r;
        int j = idx >> 5, c4 = idx & 31;
        half4_t hh;
        hh[0] = (_Float16)kv[r].x; hh[1] = (_Float16)kv[r].y;
        hh[2] = (_Float16)kv[r].z; hh[3] = (_Float16)kv[r].w;
        *(half4_t*)&kl[j][c4 * 4] = hh;
    }
    __syncthreads();

    // ---- 5. k norms + mask bias: thread t owns row t ----
    {
        float ss = 0.f;
        #pragma unroll
        for (int p = 0; p < 16; ++p) {
            half8 hh = *(const half8*)&kl[t][p * 8];
            #pragma unroll
            for (int e = 0; e < 8; ++e) {
                float x = (float)hh[e];
                ss = fmaf(x, x, ss);
            }
        }
        rk[t]  = 1.0f / fmaxf(sqrtf(ss), 1e-12f);
        bjs[t] = (km != 0) ? -1e30f : 0.0f;
    }
    // visibility of rk/bjs covered by the first in-loop barrier

    const float scale  = fminf(__expf(ls), 100.0f);
    const float inv_ln = 1.0f / (sqrtf((float)(LQ * LK)) + 1e-6f);

    // ---- 6. live b's in pairs (B fragments shared across the pair) ----
    unsigned long long mrem = mball;
    for (int m0 = 0; m0 < M; m0 += 2) {
        const int b0 = (int)__builtin_ctzll(mrem); mrem &= mrem - 1ull;
        int b1 = b0;
        if (m0 + 1 < M) { b1 = (int)__builtin_ctzll(mrem); mrem &= mrem - 1ull; }

        // stage q[b0], q[b1] -> f16 LDS (b1==b0 duplicate is harmless)
        const float4* qg0 = (const float4*)(q + (size_t)b0 * LQ * D_);
        const float4* qg1 = (const float4*)(q + (size_t)b1 * LQ * D_);
        #pragma unroll
        for (int r = 0; r < 4; ++r) {
            int idx = t + 256 * r;                 // [32][32] float4
            float4 v0 = qg0[idx];
            float4 v1 = qg1[idx];
            int i = idx >> 5, c4 = idx & 31;
            half4_t h0, h1;
            h0[0] = (_Float16)v0.x; h0[1] = (_Float16)v0.y;
            h0[2] = (_Float16)v0.z; h0[3] = (_Float16)v0.w;
            h1[0] = (_Float16)v1.x; h1[1] = (_Float16)v1.y;
            h1[2] = (_Float16)v1.z; h1[3] = (_Float16)v1.w;
            *(half4_t*)&ql2[0][i][c4 * 4] = h0;
            *(half4_t*)&ql2[1][i][c4 * 4] = h1;
        }
        __syncthreads();                           // ql2 (+rk/bjs on iter 0)

        // q norms: t<64 covers both pair members (pb = t>>5, i = t&31)
        if (t < 64) {
            const int pb = t >> 5, i = t & 31;
            float ss = 0.f;
            #pragma unroll
            for (int p = 0; p < 16; ++p) {
                half8 hh = *(const half8*)&ql2[pb][i][p * 8];
                #pragma unroll
                for (int e = 0; e < 8; ++e) {
                    float x = (float)hh[e];
                    ss = fmaf(x, x, ss);
                }
            }
            rqa2[pb][i] = ALPHA / fmaxf(sqrtf(ss), 1e-12f);
        }
        __syncthreads();

        // MFMA: wave w -> rows [16*(w>>1), +16), cols [(w&1)*128, +128)
        const int i0 = (w >> 1) * 16;
        const int j0 = (w & 1) * 128;

        half8 afrag[2][4];
        #pragma unroll
        for (int pb = 0; pb < 2; ++pb)
            #pragma unroll
            for (int kk = 0; kk < 4; ++kk)
                afrag[pb][kk] =
                    *(const half8*)&ql2[pb][i0 + row16][kk * 32 + quad * 8];

        float rqv[2][4];
        #pragma unroll
        for (int pb = 0; pb < 2; ++pb)
            #pragma unroll
            for (int rg = 0; rg < 4; ++rg)
                rqv[pb][rg] = rqa2[pb][i0 + quad * 4 + rg];

        float esum[2][4] = {{0.f,0.f,0.f,0.f},{0.f,0.f,0.f,0.f}};
        #pragma unroll
        for (int c = 0; c < 8; ++c) {
            const int jt = j0 + c * 16;
            f32x4 acc0 = {0.f, 0.f, 0.f, 0.f};
            f32x4 acc1 = {0.f, 0.f, 0.f, 0.f};
            #pragma unroll
            for (int kk = 0; kk < 4; ++kk) {
                half8 bfrag =
                    *(const half8*)&kl[jt + row16][kk * 32 + quad * 8];
                acc0 = __builtin_amdgcn_mfma_f32_16x16x32_f16(
                           afrag[0][kk], bfrag, acc0, 0, 0, 0);
                acc1 = __builtin_amdgcn_mfma_f32_16x16x32_f16(
                           afrag[1][kk], bfrag, acc1, 0, 0, 0);
            }
            // C layout: col = lane&15 (j), row = quad*4+reg (i)
            const float rkj = rk[jt + row16];
            const float bb  = bjs[jt + row16];
            #pragma unroll
            for (int rg = 0; rg < 4; ++rg) {
                esum[0][rg] += __expf(acc0[rg] * rqv[0][rg] * rkj + bb);
                esum[1][rg] += __expf(acc1[rg] * rqv[1][rg] * rkj + bb);
            }
        }
        #pragma unroll
        for (int pb = 0; pb < 2; ++pb) {
            #pragma unroll
            for (int rg = 0; rg < 4; ++rg) {
                float e = esum[pb][rg];
                e += __shfl_xor(e, 1);
                e += __shfl_xor(e, 2);
                e += __shfl_xor(e, 4);
                e += __shfl_xor(e, 8);
                esum[pb][rg] = e;
            }
            if (row16 == 0)
                #pragma unroll
                for (int rg = 0; rg < 4; ++rg)
                    part2[pb][w & 1][i0 + quad * 4 + rg] = esum[pb][rg];
        }
        __syncthreads();

        // finalize both pair members: wave 0 (b1==b0 double-write is benign)
        if (t < 64) {
            const int pb = t >> 5, i = t & 31;     // lane 0..31 -> pb 0
            float s = part2[pb][0][i] + part2[pb][1][i];
            bool badrow = (s <= 0.f);              // row fully k-masked
            float lse = __logf(fmaxf(s, 1e-38f));
            // reduce within each 32-lane half independently
            float tot = lse;
            tot += __shfl_xor(tot, 16);
            tot += __shfl_xor(tot, 8);
            tot += __shfl_xor(tot, 4);
            tot += __shfl_xor(tot, 2);
            tot += __shfl_xor(tot, 1);
            unsigned long long zb = __ballot(badrow);
            if (i == 0) {
                unsigned long long half_mask =
                    (pb == 0) ? 0xFFFFFFFFull : 0xFFFFFFFF00000000ull;
                float res = 0.f;
                if ((zb & half_mask) == 0ull)
                    res = (tot * (1.0f / ALPHA)) * inv_ln * scale;
                out[((pb == 0) ? b0 : b1) * O_ + o] = res;
            }
        }
        // next-iter q staging writes ql2 only; part2 reads happen before the
        // next barrier gate on the writing waves — same structure as R4.
    }
}

extern "C" void kernel_launch(void* const* d_in, const int* in_sizes, int n_in,
                              void* d_out, int out_size, void* d_ws, size_t ws_size,
                              hipStream_t stream) {
    const float* q           = (const float*)d_in[0];
    const float* k           = (const float*)d_in[1];
    const int*   q_mask      = (const int*)d_in[2];
    const int*   k_mask      = (const int*)d_in[3];
    const float* logit_scale = (const float*)d_in[4];
    float* out = (float*)d_out;

    colbert_fused_kernel<<<O_, 256, 0, stream>>>(q, k, q_mask, k_mask,
                                                 logit_scale, out);
}

// Round 7
// 75.286 us; speedup vs baseline: 1.0635x; 1.0224x over previous
//
#include <hip/hip_runtime.h>
#include <math.h>

// ColBERT pairwise late-interaction score — single fused kernel (R7).
//
// out[b,o] = scale/sqrt(Lq*Lk) * sum_i log(sum_j exp(alpha*qn[b,i].kn[o,j]))/alpha
// Row b is exactly zero if any q_mask[b,i] (reference isfinite guard) -> only
// M ~ 2-3 of 64 b's are live.
//
// R7 = R6 minus falsified "optimizations", plus critical-path overlap:
//   1. ONLY wave 0 reads q_mask (8 KB scattered). Waves 1-3 issue k loads
//      immediately (R6 had all 4 waves each pull 8 KB of masks before k).
//      Wave 0 publishes {M, live-b list} via LDS at the existing k barrier.
//   2. After the k barrier, q[b0]/q[b1] global loads are issued BEFORE the
//      k-norm phase, so their HBM latency hides under norm DS/VALU work.
//   (R6 bank-conflict analysis was wrong: the 272 B row stride gives uniform
//    bank load on frag AND norm reads; LDS is ~1.6 us total, not the wall.)
//
// Numerics: S <= 1 (cosine) -> alpha*S <= 12, exp never overflows; masked j
// add -1e30 before exp -> exact 0; valid j >= e^-12 so rowsum == 0 iff row
// fully k-masked (-inf -> zero). f16 input rounding ~1e-3 vs 5.1e-2 threshold.

#define ALPHA 12.0f

constexpr int B_  = 64;
constexpr int LQ  = 32;
constexpr int O_  = 128;
constexpr int LK  = 256;
constexpr int D_  = 128;
constexpr int LDH = D_ + 8;        // f16 row stride 136 (272 B), 16B-aligned

typedef _Float16 half8   __attribute__((ext_vector_type(8)));
typedef _Float16 half4_t __attribute__((ext_vector_type(4)));
typedef float    f32x4   __attribute__((ext_vector_type(4)));

__global__ __launch_bounds__(256, 1)
void colbert_fused_kernel(const float* __restrict__ q,       // [B, Lq, D]
                          const float* __restrict__ k,       // [O, Lk, D]
                          const int*  __restrict__ q_mask,   // [B, Lq] 0/1
                          const int*  __restrict__ k_mask,   // [O, Lk] 0/1
                          const float* __restrict__ logit_scale,
                          float* __restrict__ out)           // [B, O]
{
    __shared__ _Float16 kl[LK][LDH];        // 69632 B
    __shared__ _Float16 ql2[2][LQ][LDH];    // 17408 B (pair of q tiles)
    __shared__ float rk[LK];                // 1/||k_j||
    __shared__ float bjs[LK];               // 0 or -1e30
    __shared__ float rqa2[2][LQ];           // ALPHA/||q_i||
    __shared__ float part2[2][2][LQ];       // [pair][col-half][row]
    __shared__ int   lbm[B_ + 1];           // [0]=M, [1+m]=live b

    const int o     = blockIdx.x;
    const int t     = threadIdx.x;
    const int lane  = t & 63;
    const int w     = t >> 6;
    const int row16 = lane & 15;
    const int quad  = lane >> 4;

    // ---- wave 0 ONLY: q_mask scan + ballot + dead-row zeroing ----
    if (w == 0) {
        const int4* qm4 = (const int4*)q_mask;     // [64][32] ints, lane = b
        int4 mm[8];
        #pragma unroll
        for (int u = 0; u < 8; ++u)
            mm[u] = qm4[lane * 8 + u];
        int any = 0;
        #pragma unroll
        for (int u = 0; u < 8; ++u)
            any |= mm[u].x | mm[u].y | mm[u].z | mm[u].w;
        const bool live = (any == 0);
        unsigned long long mb = __ballot(live);
        if (live) {
            int rank = __popcll(mb & ((1ull << lane) - 1ull));
            lbm[1 + rank] = lane;
        } else {
            out[lane * O_ + o] = 0.0f;             // dead row -> exact zero
        }
        if (lane == 0) lbm[0] = (int)__popcll(mb);
    }

    // ---- all waves: k tile loads (waves 1-3 start here immediately) ----
    const float4* kg = (const float4*)(k + (size_t)o * LK * D_);
    float4 kv[16];
    #pragma unroll
    for (int r = 0; r < 16; ++r)
        kv[r] = kg[t + 256 * r];                   // rows 0..127, coalesced
    const int   km = k_mask[o * LK + t];           // row j = t
    const float ls = logit_scale[0];

    // convert half 0, load+convert half 1
    #pragma unroll
    for (int r = 0; r < 16; ++r) {
        int idx = t + 256 * r;
        int j = idx >> 5, c4 = idx & 31;
        half4_t hh;
        hh[0] = (_Float16)kv[r].x; hh[1] = (_Float16)kv[r].y;
        hh[2] = (_Float16)kv[r].z; hh[3] = (_Float16)kv[r].w;
        *(half4_t*)&kl[j][c4 * 4] = hh;
    }
    #pragma unroll
    for (int r = 0; r < 16; ++r)
        kv[r] = kg[4096 + t + 256 * r];            // rows 128..255
    #pragma unroll
    for (int r = 0; r < 16; ++r) {
        int idx = 4096 + t + 256 * r;
        int j = idx >> 5, c4 = idx & 31;
        half4_t hh;
        hh[0] = (_Float16)kv[r].x; hh[1] = (_Float16)kv[r].y;
        hh[2] = (_Float16)kv[r].z; hh[3] = (_Float16)kv[r].w;
        *(half4_t*)&kl[j][c4 * 4] = hh;
    }
    __syncthreads();                               // kl + lbm visible

    const int M = lbm[0];
    if (M == 0) return;                            // block-uniform

    const float scale  = fminf(__expf(ls), 100.0f);
    const float inv_ln = 1.0f / (sqrtf((float)(LQ * LK)) + 1e-6f);

    // ---- live b's in pairs; iteration 0 overlaps q loads with k norms ----
    int midx = 0;
    bool first = true;
    while (midx < M) {
        const int b0 = lbm[1 + midx];
        const int b1 = lbm[1 + ((midx + 1 < M) ? midx + 1 : midx)];
        midx += 2;

        // issue q[b0], q[b1] global loads FIRST (latency hides under norms)
        const float4* qg0 = (const float4*)(q + (size_t)b0 * LQ * D_);
        const float4* qg1 = (const float4*)(q + (size_t)b1 * LQ * D_);
        float4 qv0[4], qv1[4];
        #pragma unroll
        for (int r = 0; r < 4; ++r) {
            qv0[r] = qg0[t + 256 * r];
            qv1[r] = qg1[t + 256 * r];
        }

        // k norms + mask bias on iteration 0 (DS/VALU while q in flight)
        if (first) {
            float ss = 0.f;
            #pragma unroll
            for (int p = 0; p < 16; ++p) {
                half8 hh = *(const half8*)&kl[t][p * 8];
                #pragma unroll
                for (int e = 0; e < 8; ++e) {
                    float x = (float)hh[e];
                    ss = fmaf(x, x, ss);
                }
            }
            rk[t]  = 1.0f / fmaxf(sqrtf(ss), 1e-12f);
            bjs[t] = (km != 0) ? -1e30f : 0.0f;
            first = false;
        }

        // convert + stage q pair
        #pragma unroll
        for (int r = 0; r < 4; ++r) {
            int idx = t + 256 * r;                 // [32][32] float4
            int i = idx >> 5, c4 = idx & 31;
            half4_t h0, h1;
            h0[0] = (_Float16)qv0[r].x; h0[1] = (_Float16)qv0[r].y;
            h0[2] = (_Float16)qv0[r].z; h0[3] = (_Float16)qv0[r].w;
            h1[0] = (_Float16)qv1[r].x; h1[1] = (_Float16)qv1[r].y;
            h1[2] = (_Float16)qv1[r].z; h1[3] = (_Float16)qv1[r].w;
            *(half4_t*)&ql2[0][i][c4 * 4] = h0;
            *(half4_t*)&ql2[1][i][c4 * 4] = h1;
        }
        __syncthreads();                           // ql2 + rk/bjs visible

        // q norms: t<64 covers both pair members (pb = t>>5, i = t&31)
        if (t < 64) {
            const int pb = t >> 5, i = t & 31;
            float ss = 0.f;
            #pragma unroll
            for (int p = 0; p < 16; ++p) {
                half8 hh = *(const half8*)&ql2[pb][i][p * 8];
                #pragma unroll
                for (int e = 0; e < 8; ++e) {
                    float x = (float)hh[e];
                    ss = fmaf(x, x, ss);
                }
            }
            rqa2[pb][i] = ALPHA / fmaxf(sqrtf(ss), 1e-12f);
        }
        __syncthreads();

        // MFMA: wave w -> rows [16*(w>>1), +16), cols [(w&1)*128, +128)
        const int i0 = (w >> 1) * 16;
        const int j0 = (w & 1) * 128;

        half8 afrag[2][4];
        #pragma unroll
        for (int pb = 0; pb < 2; ++pb)
            #pragma unroll
            for (int kk = 0; kk < 4; ++kk)
                afrag[pb][kk] =
                    *(const half8*)&ql2[pb][i0 + row16][kk * 32 + quad * 8];

        float rqv[2][4];
        #pragma unroll
        for (int pb = 0; pb < 2; ++pb)
            #pragma unroll
            for (int rg = 0; rg < 4; ++rg)
                rqv[pb][rg] = rqa2[pb][i0 + quad * 4 + rg];

        float esum[2][4] = {{0.f,0.f,0.f,0.f},{0.f,0.f,0.f,0.f}};
        #pragma unroll
        for (int c = 0; c < 8; ++c) {
            const int jt = j0 + c * 16;
            f32x4 acc0 = {0.f, 0.f, 0.f, 0.f};
            f32x4 acc1 = {0.f, 0.f, 0.f, 0.f};
            #pragma unroll
            for (int kk = 0; kk < 4; ++kk) {
                half8 bfrag =
                    *(const half8*)&kl[jt + row16][kk * 32 + quad * 8];
                acc0 = __builtin_amdgcn_mfma_f32_16x16x32_f16(
                           afrag[0][kk], bfrag, acc0, 0, 0, 0);
                acc1 = __builtin_amdgcn_mfma_f32_16x16x32_f16(
                           afrag[1][kk], bfrag, acc1, 0, 0, 0);
            }
            // C layout: col = lane&15 (j), row = quad*4+reg (i)
            const float rkj = rk[jt + row16];
            const float bb  = bjs[jt + row16];
            #pragma unroll
            for (int rg = 0; rg < 4; ++rg) {
                esum[0][rg] += __expf(acc0[rg] * rqv[0][rg] * rkj + bb);
                esum[1][rg] += __expf(acc1[rg] * rqv[1][rg] * rkj + bb);
            }
        }
        #pragma unroll
        for (int pb = 0; pb < 2; ++pb) {
            #pragma unroll
            for (int rg = 0; rg < 4; ++rg) {
                float e = esum[pb][rg];
                e += __shfl_xor(e, 1);
                e += __shfl_xor(e, 2);
                e += __shfl_xor(e, 4);
                e += __shfl_xor(e, 8);
                esum[pb][rg] = e;
            }
            if (row16 == 0)
                #pragma unroll
                for (int rg = 0; rg < 4; ++rg)
                    part2[pb][w & 1][i0 + quad * 4 + rg] = esum[pb][rg];
        }
        __syncthreads();

        // finalize both pair members: wave 0 (b1==b0 double-write benign)
        if (t < 64) {
            const int pb = t >> 5, i = t & 31;
            float s = part2[pb][0][i] + part2[pb][1][i];
            bool badrow = (s <= 0.f);              // row fully k-masked
            float lse = __logf(fmaxf(s, 1e-38f));
            float tot = lse;
            tot += __shfl_xor(tot, 16);
            tot += __shfl_xor(tot, 8);
            tot += __shfl_xor(tot, 4);
            tot += __shfl_xor(tot, 2);
            tot += __shfl_xor(tot, 1);
            unsigned long long zb = __ballot(badrow);
            if (i == 0) {
                unsigned long long half_mask =
                    (pb == 0) ? 0xFFFFFFFFull : 0xFFFFFFFF00000000ull;
                float res = 0.f;
                if ((zb & half_mask) == 0ull)
                    res = (tot * (1.0f / ALPHA)) * inv_ln * scale;
                out[((pb == 0) ? b0 : b1) * O_ + o] = res;
            }
        }
        // next-iter ql2 writes are gated by the barrier at loop top (the
        // __syncthreads after q staging) — same protection structure as R6.
    }
}

extern "C" void kernel_launch(void* const* d_in, const int* in_sizes, int n_in,
                              void* d_out, int out_size, void* d_ws, size_t ws_size,
                              hipStream_t stream) {
    const float* q           = (const float*)d_in[0];
    const float* k           = (const float*)d_in[1];
    const int*   q_mask      = (const int*)d_in[2];
    const int*   k_mask      = (const int*)d_in[3];
    const float* logit_scale = (const float*)d_in[4];
    float* out = (float*)d_out;

    colbert_fused_kernel<<<O_, 256, 0, stream>>>(q, k, q_mask, k_mask,
                                                 logit_scale, out);
}